// Round 11
// baseline (5597.363 us; speedup 1.0000x reference)
//
#include <hip/hip_runtime.h>
#include <hip/hip_fp16.h>

// IGIRNN persistent-scan kernel, round 11.
// r8 (3.08ms, proven) had a ~6-serial-RT/step chain: publish->drain(RT) ->
// flag store -> flag visible(RT/2) -> poll detect(RT) -> gather(RT).
// r10's sentinel cut RTs but added resets (write doubling) + full re-gather
// retries -> regressed. Round 11 = r8 with ONE change: STAMP-IN-SLOT
// transport. Publish slot = 16B [8B h | 4B stamp=t | pad], written by ONE
// global_store_dwordx4 sc0 sc1 (stamp atomic with data: single <=16B
// aligned store, one cacheline, consumed by a single 16B load). Deletes
// writer drain + flag store + flag poll. Consumer = gather-retry: 16-load
// batch (2 loads/frag: frag spans two slots), one vmcnt(0), verify all 16
// inline stamps == t. 2 slots; stamps t vs t-2 distinguish generations ->
// no resets. Overwrite-safety = r8's proof with stamps as witnesses:
// my gather of h(t) (all stamps t) => all WGs passed step-(t-1) barrier =>
// all consumed h(t-1) => slot holding h(t-1) is dead before I publish
// h(t+1) into it (after my step-t barrier).
// hbuf zeroed EVERY launch: stale stamps from a prior replay would satisfy
// the checks and defeat the sync (no cross-call state allowed).

#define BB 128
#define TT 1024
#define ID 256
#define HH 1024

using f16   = _Float16;
using f16x8 = __attribute__((ext_vector_type(8))) _Float16;
using f32x4 = __attribute__((ext_vector_type(4))) float;
typedef unsigned long long u64;

// LDS (bytes)
#define OFF_X    0        // x   [2][16][512B] f16, SWZ     = 16384
#define OFF_GX   16384    // gx  [2][4][272] f32            = 8704
#define OFF_GH   25088    // ghT [2][2][4][272] f32         = 17408
#define LDS_SIZE 42496

#define SWZ(row, kbyte) ((kbyte) ^ (((row) & 3) << 4))
#define MFMA16(a, b, c) __builtin_amdgcn_mfma_f32_16x16x32_f16(a, b, c, 0, 0, 0)

static __device__ __forceinline__ void store4h(f16* dst, float a, float b, float c, float d) {
  union { f16 h[4]; u64 u; } p;
  p.h[0] = (f16)a; p.h[1] = (f16)b; p.h[2] = (f16)c; p.h[3] = (f16)d;
  *reinterpret_cast<u64*>(dst) = p.u;
}

static __device__ __forceinline__ f16x8 cvt8(float4 a, float4 b) {
  f16x8 r;
  r[0] = (f16)a.x; r[1] = (f16)a.y; r[2] = (f16)a.z; r[3] = (f16)a.w;
  r[4] = (f16)b.x; r[5] = (f16)b.y; r[6] = (f16)b.z; r[7] = (f16)b.w;
  return r;
}

static __device__ __forceinline__ void put_tile(float* dst, f32x4 v, int lane) {
  const int c = lane & 15, r4 = (lane >> 4) * 4;
  #pragma unroll
  for (int r = 0; r < 4; ++r) dst[(r4 + r) * 17 + c] = v[r];
}

// build MFMA B-frag from two 16B slots: [A.h0 A.h1 | B.h0 B.h1]
static __device__ __forceinline__ f16x8 mkfrag(f32x4 A, f32x4 B) {
  f32x4 f; f.x = A.x; f.y = A.y; f.z = B.x; f.w = B.y;
  union { f32x4 v; f16x8 h; } u; u.v = f; return u.h;
}

__global__ __launch_bounds__(256, 1) void rnn_core(
    const float* __restrict__ x, const float* __restrict__ Wx, const float* __restrict__ bx,
    const float* __restrict__ Wh, const float* __restrict__ bh,
    f16* __restrict__ hbuf,      // [2 slot][8 grp][32 wg][2KB chunk] = 1MB
    float* __restrict__ hfin)    // [128][1024] f32
{
  extern __shared__ char lds[];
  char*  xbuf = lds + OFF_X;
  float* gxch = (float*)(lds + OFF_GX);   // [2][4][272], q = gate*2 + nt
  float* ghT  = (float*)(lds + OFF_GH);   // [2][2][4][272]: [parity][nt][src]

  const int tid  = threadIdx.x;
  const int lane = tid & 63;
  const int w    = tid >> 6;
  const int g    = blockIdx.x & 7;
  const int cw   = blockIdx.x >> 3;
  const int b0   = g * 16;
  const int j0   = cw * 32;
  const int col  = lane & 15;
  const int quad = lane >> 4;
  const int row4 = quad * 4;
  const int nt   = w >> 1;               // even waves: output ntile; odd: gx ntile

  // ---- Wh A-fragments -> registers (ALL waves; K-chunks w*8..w*8+7) ----
  f16x8 whf[16];
  #pragma unroll
  for (int n = 0; n < 2; ++n)
    #pragma unroll
    for (int i = 0; i < 8; ++i) {
      const float* p = Wh + (size_t)(j0 + n * 16 + col) * HH + ((w << 3) + i) * 32 + quad * 8;
      whf[n * 8 + i] = cvt8(*reinterpret_cast<const float4*>(p),
                            *reinterpret_cast<const float4*>(p + 4));
    }
  // ---- Wx A-fragments (odd waves; [gate][ks]) ----
  f16x8 wxf[16];
  if (w & 1) {
    #pragma unroll
    for (int g2 = 0; g2 < 2; ++g2)
      #pragma unroll
      for (int ks = 0; ks < 8; ++ks) {
        const float* p = Wx + (size_t)(g2 * HH + j0 + nt * 16 + col) * ID + ks * 32 + quad * 8;
        wxf[g2 * 8 + ks] = cvt8(*reinterpret_cast<const float4*>(p),
                                *reinterpret_cast<const float4*>(p + 4));
      }
  }

  // ---- prologue: stage x(0)->slot0, x(1)->slot1 ----
  for (int s = 0; s < 2; ++s)
    for (int c = tid; c < 1024; c += 256) {
      int row = c >> 6, k4 = c & 63;
      float4 v = *reinterpret_cast<const float4*>(
          x + ((size_t)(b0 + row) * TT + s) * ID + k4 * 4);
      store4h((f16*)(xbuf + s * 8192 + row * 512 + SWZ(row, k4 * 8)), v.x, v.y, v.z, v.w);
    }
  __syncthreads();

  // ---- prologue gx(0) (odd waves), parity 0 ----
  if (w & 1) {
    const char* pxb = xbuf + col * 512 + ((quad * 16) ^ ((col & 3) << 4));
    f32x4 a0 = {0,0,0,0}, a1 = {0,0,0,0};
    #pragma unroll
    for (int ks = 0; ks < 8; ++ks) {
      f16x8 bfr = *reinterpret_cast<const f16x8*>(pxb + ks * 64);
      a0 = MFMA16(wxf[ks], bfr, a0);
      a1 = MFMA16(wxf[8 + ks], bfr, a1);
    }
    put_tile(gxch + nt * 272, a0, lane);
    put_tile(gxch + (2 + nt) * 272, a1, lane);
  }

  // even-wave pointwise constants (j = j0 + nt*16 + row4 + r)
  float4 bh4 = {0,0,0,0}, bxr4 = {0,0,0,0}, bxi4 = {0,0,0,0};
  if (!(w & 1)) {
    bh4  = *reinterpret_cast<const float4*>(bh + j0 + nt * 16 + row4);
    bxr4 = *reinterpret_cast<const float4*>(bx + j0 + nt * 16 + row4);
    bxi4 = *reinterpret_cast<const float4*>(bx + HH + j0 + nt * 16 + row4);
  }
  float hm[4] = {0.f, 0.f, 0.f, 0.f};     // h[b0+col][j0+nt*16+row4+r]

  // invariant addresses. slot stride 512KB; group 64KB; chunk 2KB.
  // gather lane voff = col*128 + q*32 (frag slots at +0 and +16).
  const unsigned gvo = (unsigned)(col * 128 + quad * 32);
  const u64 gb0 = (u64)((const char*)hbuf + (size_t)g * 65536 + (size_t)(w << 3) * 2048) + gvo;
  const u64 gb1 = gb0 + 524288;
  // publish slot: col*128 + nt*64 + quad*16
  const u64 pb0 = (u64)((char*)hbuf + (size_t)g * 65536 + (size_t)cw * 2048
                        + (unsigned)(col * 128 + nt * 64 + quad * 16));
  const u64 pb1 = pb0 + 524288;

  for (int t = 0; t < TT; ++t) {
    const int p = t & 1;
    // ======== region A: gather-retry (stamps==t) -> 16 MFMAs ========
    f32x4 acc0 = {0,0,0,0}, acc1 = {0,0,0,0};
    if (t > 0) {
      const u64 ad0 = (p ? gb1 : gb0);
      const u64 ad1 = ad0 + 4096, ad2 = ad0 + 8192, ad3 = ad0 + 12288;
      const unsigned ut = (unsigned)t;
      f32x4 A0,B0,A1,B1,A2,B2,A3,B3,A4,B4,A5,B5,A6,B6,A7,B7;
      for (;;) {
        asm volatile(
          "global_load_dwordx4 %0, %16, off sc0 sc1\n\t"
          "global_load_dwordx4 %1, %16, off offset:16 sc0 sc1\n\t"
          "global_load_dwordx4 %2, %16, off offset:2048 sc0 sc1\n\t"
          "global_load_dwordx4 %3, %16, off offset:2064 sc0 sc1\n\t"
          "global_load_dwordx4 %4, %17, off sc0 sc1\n\t"
          "global_load_dwordx4 %5, %17, off offset:16 sc0 sc1\n\t"
          "global_load_dwordx4 %6, %17, off offset:2048 sc0 sc1\n\t"
          "global_load_dwordx4 %7, %17, off offset:2064 sc0 sc1\n\t"
          "global_load_dwordx4 %8, %18, off sc0 sc1\n\t"
          "global_load_dwordx4 %9, %18, off offset:16 sc0 sc1\n\t"
          "global_load_dwordx4 %10, %18, off offset:2048 sc0 sc1\n\t"
          "global_load_dwordx4 %11, %18, off offset:2064 sc0 sc1\n\t"
          "global_load_dwordx4 %12, %19, off sc0 sc1\n\t"
          "global_load_dwordx4 %13, %19, off offset:16 sc0 sc1\n\t"
          "global_load_dwordx4 %14, %19, off offset:2048 sc0 sc1\n\t"
          "global_load_dwordx4 %15, %19, off offset:2064 sc0 sc1\n\t"
          "s_waitcnt vmcnt(0)"
          : "=&v"(A0), "=&v"(B0), "=&v"(A1), "=&v"(B1),
            "=&v"(A2), "=&v"(B2), "=&v"(A3), "=&v"(B3),
            "=&v"(A4), "=&v"(B4), "=&v"(A5), "=&v"(B5),
            "=&v"(A6), "=&v"(B6), "=&v"(A7), "=&v"(B7)
          : "v"(ad0), "v"(ad1), "v"(ad2), "v"(ad3)
          : "memory");
        bool ok = (__float_as_uint(A0.z) == ut) && (__float_as_uint(B0.z) == ut)
               && (__float_as_uint(A1.z) == ut) && (__float_as_uint(B1.z) == ut)
               && (__float_as_uint(A2.z) == ut) && (__float_as_uint(B2.z) == ut)
               && (__float_as_uint(A3.z) == ut) && (__float_as_uint(B3.z) == ut)
               && (__float_as_uint(A4.z) == ut) && (__float_as_uint(B4.z) == ut)
               && (__float_as_uint(A5.z) == ut) && (__float_as_uint(B5.z) == ut)
               && (__float_as_uint(A6.z) == ut) && (__float_as_uint(B6.z) == ut)
               && (__float_as_uint(A7.z) == ut) && (__float_as_uint(B7.z) == ut);
        if (__all(ok)) break;
      }
      #define STEPM(i, A, B) { f16x8 bf_ = mkfrag(A, B); \
        acc0 = MFMA16(whf[i], bf_, acc0); acc1 = MFMA16(whf[8 + (i)], bf_, acc1); }
      STEPM(0, A0, B0) STEPM(1, A1, B1) STEPM(2, A2, B2) STEPM(3, A3, B3)
      STEPM(4, A4, B4) STEPM(5, A5, B5) STEPM(6, A6, B6) STEPM(7, A7, B7)
      #undef STEPM
    }
    // export partials (slot = src wave); even waves keep own-nt in register
    float* ghp = ghT + p * 2176;
    if (w == 0)      { put_tile(ghp + (4 + 0) * 272, acc1, lane); }
    else if (w == 1) { put_tile(ghp + 1 * 272, acc0, lane);
                       put_tile(ghp + (4 + 1) * 272, acc1, lane); }
    else if (w == 2) { put_tile(ghp + 2 * 272, acc0, lane); }
    else             { put_tile(ghp + 3 * 272, acc0, lane);
                       put_tile(ghp + (4 + 3) * 272, acc1, lane); }

    __syncthreads();                                  // the ONE barrier/step

    // ======== region B ========
    if (!(w & 1)) {
      // reduce 3 partials + own, pointwise, publish (single stamped store)
      const float* basep = ghp + nt * 4 * 272;
      const float* s0 = basep + ((w == 0) ? 1 : 0) * 272;
      const float* s1 = basep + ((w == 0) ? 2 : 1) * 272;
      const float* s2 = basep + 3 * 272;
      const float* gxr = gxch + p * 1088 + nt * 272;
      const float* gxi = gxch + p * 1088 + (2 + nt) * 272;
      f32x4 own = (w == 0) ? acc0 : acc1;
      float hn[4];
      #pragma unroll
      for (int r = 0; r < 4; ++r) {
        int idx = (row4 + r) * 17 + col;
        float ghf = own[r] + s0[idx] + s1[idx] + s2[idx] + ((const float*)&bh4)[r];
        float ir  = gxr[idx] + ((const float*)&bxr4)[r];
        float ii  = gxi[idx] + ((const float*)&bxi4)[r];
        float rg  = 1.f / (1.f + __expf(-ir));
        float ig  = 1.f / (1.f + __expf(-ii));
        float z   = rg * ghf;
        z = fminf(fmaxf(z, -15.f), 15.f);
        float e   = __expf(-2.f * z);
        float ng  = (1.f - e) / (1.f + e);
        float h_  = ng + ig * (hm[r] - ng);
        hm[r] = h_; hn[r] = h_;
      }
      union { f16 h[4]; unsigned u[2]; } hp;
      hp.h[0] = (f16)hn[0]; hp.h[1] = (f16)hn[1]; hp.h[2] = (f16)hn[2]; hp.h[3] = (f16)hn[3];
      f32x4 pv;
      pv.x = __uint_as_float(hp.u[0]); pv.y = __uint_as_float(hp.u[1]);
      pv.z = __uint_as_float((unsigned)(t + 1)); pv.w = pv.z;
      const u64 adp = (p ? pb0 : pb1);                // h(t+1) -> slot (t+1)&1
      asm volatile("global_store_dwordx4 %0, %1, off sc0 sc1"
                   :: "v"(adp), "v"(pv) : "memory");
      // no drain, no flag: stamp rides with the data.
    } else {
      // gx(t+1) -> gxch parity (t+1)&1
      if (t + 1 < TT) {
        const char* pxb = xbuf + ((t + 1) & 1) * 8192 + col * 512
                          + ((quad * 16) ^ ((col & 3) << 4));
        f32x4 a0 = {0,0,0,0}, a1 = {0,0,0,0};
        #pragma unroll
        for (int ks = 0; ks < 8; ++ks) {
          f16x8 bfr = *reinterpret_cast<const f16x8*>(pxb + ks * 64);
          a0 = MFMA16(wxf[ks], bfr, a0);
          a1 = MFMA16(wxf[8 + ks], bfr, a1);
        }
        float* gdst = gxch + ((t + 1) & 1) * 1088;
        put_tile(gdst + nt * 272, a0, lane);
        put_tile(gdst + (2 + nt) * 272, a1, lane);
      }
      // x(t+2) prefetch -> slot t&1 (w1 rows 0-7, w3 rows 8-15)
      if (t + 2 < TT) {
        char* xd = xbuf + p * 8192;
        #pragma unroll
        for (int it = 0; it < 8; ++it) {
          int row = nt * 8 + it;
          float4 v = *reinterpret_cast<const float4*>(
              x + ((size_t)(b0 + row) * TT + (t + 2)) * ID + lane * 4);
          store4h((f16*)(xd + row * 512 + SWZ(row, lane * 8)), v.x, v.y, v.z, v.w);
        }
      }
    }
  }

  // ---- final h export ----
  if (!(w & 1)) {
    float4 o; o.x = hm[0]; o.y = hm[1]; o.z = hm[2]; o.w = hm[3];
    *reinterpret_cast<float4*>(hfin + (size_t)(b0 + col) * HH + j0 + nt * 16 + row4) = o;
  }
}

// out[b][o] = hfin[b][:] . Wfc[o][:] + bfc[o];  128x256, K=1024.
__global__ __launch_bounds__(64) void fc_kernel(
    const float* __restrict__ hfin, const float* __restrict__ Wfc,
    const float* __restrict__ bfc, float* __restrict__ out)
{
  const int lane = threadIdx.x;
  const int mb = blockIdx.x >> 4, nb = blockIdx.x & 15;
  const int col = lane & 15, row4 = (lane >> 4) * 4;
  const float* pa = hfin + (size_t)(mb * 16 + (lane & 15)) * HH + (lane >> 4) * 8;
  const float* pb = Wfc  + (size_t)(nb * 16 + (lane & 15)) * HH + (lane >> 4) * 8;
  f32x4 acc = {0.f, 0.f, 0.f, 0.f};
  for (int kc = 0; kc < 32; ++kc) {
    f16x8 a, b;
    #pragma unroll
    for (int e = 0; e < 8; ++e) {
      a[e] = (f16)pa[kc * 32 + e];
      b[e] = (f16)pb[kc * 32 + e];
    }
    acc = __builtin_amdgcn_mfma_f32_16x16x32_f16(a, b, acc, 0, 0, 0);
  }
  float bias = bfc[nb * 16 + col];
  #pragma unroll
  for (int r = 0; r < 4; ++r)
    out[(size_t)(mb * 16 + row4 + r) * 256 + nb * 16 + col] = acc[r] + bias;
}

extern "C" void kernel_launch(void* const* d_in, const int* in_sizes, int n_in,
                              void* d_out, int out_size, void* d_ws, size_t ws_size,
                              hipStream_t stream) {
  const float* x   = (const float*)d_in[0];
  const float* Wx  = (const float*)d_in[1];
  const float* bx  = (const float*)d_in[2];
  const float* Wh  = (const float*)d_in[3];
  const float* bh  = (const float*)d_in[4];
  const float* Wfc = (const float*)d_in[5];
  const float* bfc = (const float*)d_in[6];
  float* out = (float*)d_out;

  char* ws = (char*)d_ws;
  f16*   hbuf = (f16*)ws;                  // 1MB: 2 slots x 512KB (16B slots)
  float* hfin = (float*)(ws + 1048576);    // 512KB

  // zero stamps every launch: stale stamps from a prior (identical) replay
  // would satisfy the checks and defeat the sync -> must not rely on
  // left-behind state. Stamp 0 never matches t>=1.
  hipMemsetAsync(hbuf, 0, 1048576, stream);

  (void)hipFuncSetAttribute((const void*)rnn_core,
                            hipFuncAttributeMaxDynamicSharedMemorySize, LDS_SIZE);

  void* args[7];
  args[0] = (void*)&x;    args[1] = (void*)&Wx;   args[2] = (void*)&bx;
  args[3] = (void*)&Wh;   args[4] = (void*)&bh;   args[5] = (void*)&hbuf;
  args[6] = (void*)&hfin;
  hipError_t err = hipLaunchCooperativeKernel((void*)rnn_core, dim3(256), dim3(256),
                                              args, LDS_SIZE, stream);
  if (err != hipSuccess) {
    rnn_core<<<dim3(256), dim3(256), LDS_SIZE, stream>>>(x, Wx, bx, Wh, bh, hbuf, hfin);
  }

  fc_kernel<<<dim3(128), dim3(64), 0, stream>>>(hfin, Wfc, bfc, out);
}

// Round 13
// 4847.496 us; speedup vs baseline: 1.1547x; 1.1547x over previous
//
#include <hip/hip_runtime.h>
#include <hip/hip_fp16.h>

// IGIRNN persistent-scan kernel, round 13 (= round-12 design, occupancy fix).
// r12 failed to LAUNCH (silently): 1024-thr WG = 16 waves/CU sharing the
// 2048-VGPR/CU pool caps 128 VGPR/wave; kernel needs ~390. Both launch
// paths failed unchecked; fc_kernel ran on poisoned hfin -> absmax 1.63
// (~= bias-only output, instant fail). Fix: 256-thr WGs (4 waves), 128 WGs,
// 1/CU -> 512 VGPR/wave available.
// Wave-autonomous structure (unchanged from r12):
//  - 8 groups x 16 WGs x 4 waves; wave wid=(blockIdx>>3)*4+w owns j-tile
//    [wid*16,+16) with FULL K in registers (whf 128 VGPR + wxf 64 VGPR).
//  - Per step per wave: poll 64 flags (1/lane) -> 32-frag gather to regs
//    (2 asm blocks, one vmcnt(0) + sched_barrier(0), rule-18) -> 32 MFMA
//    -> pointwise (C-layout == ownership) -> publish 8B/lane ->
//    gx(t+1) + x(t+3) staged under the publish drain -> vmcnt+lgkmcnt(0)
//    -> flag. NO barriers in the loop.
//  - x in LDS, 4-slot rotation, 4 rows staged per wave; safety from the
//    flag drift bound: poll>=t => all 64 group waves (incl. same-WG)
//    completed step t-1 => slot writes/reads >=2 steps back retired.
//  - Transport protocol = r8's proven one: sc0 sc1 system-scope, drain
//    before flag, monotone stamps, flags zeroed each launch.

#define BB 128
#define TT 1024
#define ID 256
#define HH 1024

using f16   = _Float16;
using f16x8 = __attribute__((ext_vector_type(8))) _Float16;
using f32x4 = __attribute__((ext_vector_type(4))) float;
typedef unsigned long long u64;

#define LDS_SIZE 32768    // x [4 slot][16 row][512B]
#define SWZ(row, kbyte) ((kbyte) ^ (((row) & 3) << 4))
#define MFMA16(a, b, c) __builtin_amdgcn_mfma_f32_16x16x32_f16(a, b, c, 0, 0, 0)

static __device__ __forceinline__ void store4h(f16* dst, float a, float b, float c, float d) {
  union { f16 h[4]; u64 u; } p;
  p.h[0] = (f16)a; p.h[1] = (f16)b; p.h[2] = (f16)c; p.h[3] = (f16)d;
  *reinterpret_cast<u64*>(dst) = p.u;
}

static __device__ __forceinline__ f16x8 cvt8(float4 a, float4 b) {
  f16x8 r;
  r[0] = (f16)a.x; r[1] = (f16)a.y; r[2] = (f16)a.z; r[3] = (f16)a.w;
  r[4] = (f16)b.x; r[5] = (f16)b.y; r[6] = (f16)b.z; r[7] = (f16)b.w;
  return r;
}

// 16 fragment loads (sc0 sc1), NO wait: 4 base addrs x offsets {0,1K,2K,3K}
#define GLD16(F0,F1,F2,F3,F4,F5,F6,F7,F8,F9,Fa,Fb,Fc,Fd,Fe,Ff, A0,A1,A2,A3) \
  asm volatile( \
    "global_load_dwordx4 %0, %16, off sc0 sc1\n\t" \
    "global_load_dwordx4 %1, %16, off offset:1024 sc0 sc1\n\t" \
    "global_load_dwordx4 %2, %16, off offset:2048 sc0 sc1\n\t" \
    "global_load_dwordx4 %3, %16, off offset:3072 sc0 sc1\n\t" \
    "global_load_dwordx4 %4, %17, off sc0 sc1\n\t" \
    "global_load_dwordx4 %5, %17, off offset:1024 sc0 sc1\n\t" \
    "global_load_dwordx4 %6, %17, off offset:2048 sc0 sc1\n\t" \
    "global_load_dwordx4 %7, %17, off offset:3072 sc0 sc1\n\t" \
    "global_load_dwordx4 %8, %18, off sc0 sc1\n\t" \
    "global_load_dwordx4 %9, %18, off offset:1024 sc0 sc1\n\t" \
    "global_load_dwordx4 %10, %18, off offset:2048 sc0 sc1\n\t" \
    "global_load_dwordx4 %11, %18, off offset:3072 sc0 sc1\n\t" \
    "global_load_dwordx4 %12, %19, off sc0 sc1\n\t" \
    "global_load_dwordx4 %13, %19, off offset:1024 sc0 sc1\n\t" \
    "global_load_dwordx4 %14, %19, off offset:2048 sc0 sc1\n\t" \
    "global_load_dwordx4 %15, %19, off offset:3072 sc0 sc1\n\t" \
    : "=&v"(F0), "=&v"(F1), "=&v"(F2), "=&v"(F3), \
      "=&v"(F4), "=&v"(F5), "=&v"(F6), "=&v"(F7), \
      "=&v"(F8), "=&v"(F9), "=&v"(Fa), "=&v"(Fb), \
      "=&v"(Fc), "=&v"(Fd), "=&v"(Fe), "=&v"(Ff) \
    : "v"(A0), "v"(A1), "v"(A2), "v"(A3) : "memory")

__global__ __launch_bounds__(256, 1) void rnn_core(
    const float* __restrict__ x, const float* __restrict__ Wx, const float* __restrict__ bx,
    const float* __restrict__ Wh, const float* __restrict__ bh,
    f16* __restrict__ hbuf,      // [2 slot][8 grp][64 tile][512B] = 512KB
    float* __restrict__ hfin,    // [128][1024] f32
    int* __restrict__ flags)     // [8 grp][64 wave] stamps, 64B-strided
{
  extern __shared__ char lds[];
  char* xbuf = lds;                       // [4][16][512B], SWZ

  const int tid  = threadIdx.x;
  const int lane = tid & 63;
  const int w    = tid >> 6;              // 0..3
  const int g    = blockIdx.x & 7;
  const int wgl  = blockIdx.x >> 3;       // 0..15
  const int wid  = wgl * 4 + w;           // tile/writer id 0..63
  const int b0   = g * 16;
  const int j0w  = wid * 16;
  const int col  = lane & 15;
  const int quad = lane >> 4;
  const int row4 = quad * 4;

  // ---- Wh A-fragments (full K): whf[c] = Wh[j0w+col][c*32 + quad*8 ..+8] ----
  f16x8 whf[32];
  #pragma unroll
  for (int c = 0; c < 32; ++c) {
    const float* p = Wh + (size_t)(j0w + col) * HH + c * 32 + quad * 8;
    whf[c] = cvt8(*reinterpret_cast<const float4*>(p),
                  *reinterpret_cast<const float4*>(p + 4));
  }
  // ---- Wx A-fragments: own j-tile, both gates ----
  f16x8 wxf[16];
  #pragma unroll
  for (int gt = 0; gt < 2; ++gt)
    #pragma unroll
    for (int ks = 0; ks < 8; ++ks) {
      const float* p = Wx + (size_t)(gt * HH + j0w + col) * ID + ks * 32 + quad * 8;
      wxf[gt * 8 + ks] = cvt8(*reinterpret_cast<const float4*>(p),
                              *reinterpret_cast<const float4*>(p + 4));
    }

  // biases at j = j0w + row4 + r
  const float4 bh4  = *reinterpret_cast<const float4*>(bh + j0w + row4);
  const float4 bxr4 = *reinterpret_cast<const float4*>(bx + j0w + row4);
  const float4 bxi4 = *reinterpret_cast<const float4*>(bx + HH + j0w + row4);

  // ---- prologue: wave w stages x rows 4w..4w+3 for slots 0,1,2 ----
  #pragma unroll
  for (int s = 0; s < 3; ++s)
    #pragma unroll
    for (int rr = 0; rr < 4; ++rr) {
      int row = w * 4 + rr;
      float4 v = *reinterpret_cast<const float4*>(
          x + ((size_t)(b0 + row) * TT + s) * ID + lane * 4);
      store4h((f16*)(xbuf + s * 8192 + row * 512 + SWZ(row, lane * 8)), v.x, v.y, v.z, v.w);
    }
  __syncthreads();                         // the ONLY barrier

  // ---- gx(0) -> register set A ----
  f32x4 gxrA = {0,0,0,0}, gxiA = {0,0,0,0}, gxrB = {0,0,0,0}, gxiB = {0,0,0,0};
  {
    const char* pxb = xbuf + col * 512 + ((quad * 16) ^ ((col & 3) << 4));
    #pragma unroll
    for (int ks = 0; ks < 8; ++ks) {
      f16x8 bfr = *reinterpret_cast<const f16x8*>(pxb + ks * 64);
      gxrA = MFMA16(wxf[ks], bfr, gxrA);
      gxiA = MFMA16(wxf[8 + ks], bfr, gxiA);
    }
  }

  float hm[4] = {0.f, 0.f, 0.f, 0.f};      // h[b0+col][j0w+row4+r]

  // invariant addresses (slot stride 256KB)
  const u64 gb = (u64)((const char*)hbuf + (size_t)g * 32768)
               + (unsigned)((quad >> 1) * 512 + col * 32 + (quad & 1) * 16);
  const u64 pb = (u64)((char*)hbuf + (size_t)g * 32768 + (size_t)wid * 512
                       + (unsigned)(col * 32 + quad * 8));
  int* myflag = flags + (g * 64 + wid) * 16;
  const int* pollp = flags + (g * 64 + lane) * 16;

  for (int t = 0; t < TT; ++t) {
    const int p = t & 1;
    // ======== poll + gather + 32 MFMA (all wave-local) ========
    f32x4 acc0 = {0,0,0,0}, acc1 = {0,0,0,0};
    if (t > 0) {
      int v;
      do { v = __hip_atomic_load(pollp, __ATOMIC_RELAXED, __HIP_MEMORY_SCOPE_SYSTEM);
      } while (!__all(v >= t));

      const u64 a0 = gb + (p ? 262144u : 0u);
      const u64 a1 = a0 + 4096,  a2 = a0 + 8192,  a3 = a0 + 12288;
      const u64 a4 = a0 + 16384, a5 = a0 + 20480, a6 = a0 + 24576, a7 = a0 + 28672;
      f32x4 f0,f1,f2,f3,f4,f5,f6,f7,f8,f9,fa,fb,fc,fd,fe,ff;
      f32x4 h0,h1,h2,h3,h4,h5,h6,h7,h8,h9,ha,hb,hc,hd,he,hf;
      GLD16(f0,f1,f2,f3,f4,f5,f6,f7,f8,f9,fa,fb,fc,fd,fe,ff, a0,a1,a2,a3);
      GLD16(h0,h1,h2,h3,h4,h5,h6,h7,h8,h9,ha,hb,hc,hd,he,hf, a4,a5,a6,a7);
      asm volatile("s_waitcnt vmcnt(0)" ::: "memory");
      __builtin_amdgcn_sched_barrier(0);   // rule-18: pin MFMAs below the wait

      #define M0(i, F) { acc0 = MFMA16(whf[i], *reinterpret_cast<f16x8*>(&F), acc0); }
      #define M1(i, F) { acc1 = MFMA16(whf[i], *reinterpret_cast<f16x8*>(&F), acc1); }
      M0(0,f0)  M1(16,h0) M0(1,f1)  M1(17,h1) M0(2,f2)  M1(18,h2) M0(3,f3)  M1(19,h3)
      M0(4,f4)  M1(20,h4) M0(5,f5)  M1(21,h5) M0(6,f6)  M1(22,h6) M0(7,f7)  M1(23,h7)
      M0(8,f8)  M1(24,h8) M0(9,f9)  M1(25,h9) M0(10,fa) M1(26,ha) M0(11,fb) M1(27,hb)
      M0(12,fc) M1(28,hc) M0(13,fd) M1(29,hd) M0(14,fe) M1(30,he) M0(15,ff) M1(31,hf)
      #undef M0
      #undef M1
    }

    // ======== pointwise (gx in registers; C-layout == ownership) ========
    {
      f32x4 cgr = p ? gxrB : gxrA;
      f32x4 cgi = p ? gxiB : gxiA;
      float hn[4];
      #pragma unroll
      for (int r = 0; r < 4; ++r) {
        float ghf = acc0[r] + acc1[r] + ((const float*)&bh4)[r];
        float ir  = cgr[r] + ((const float*)&bxr4)[r];
        float ii  = cgi[r] + ((const float*)&bxi4)[r];
        float rg  = 1.f / (1.f + __expf(-ir));
        float ig  = 1.f / (1.f + __expf(-ii));
        float z   = rg * ghf;
        z = fminf(fmaxf(z, -15.f), 15.f);
        float e   = __expf(-2.f * z);
        float ng  = (1.f - e) / (1.f + e);
        float h_  = ng + ig * (hm[r] - ng);
        hm[r] = h_; hn[r] = h_;
      }
      union { f16 h[4]; u64 uu; } pk;
      pk.h[0] = (f16)hn[0]; pk.h[1] = (f16)hn[1]; pk.h[2] = (f16)hn[2]; pk.h[3] = (f16)hn[3];
      u64* adp = (u64*)(pb + ((p ^ 1) ? 262144u : 0u));   // h(t+1) -> slot (t+1)&1
      __hip_atomic_store(adp, pk.uu, __ATOMIC_RELAXED, __HIP_MEMORY_SCOPE_SYSTEM);
      // publish RT drains under gx/stage below
    }

    // ======== gx(t+1) + x(t+3) staging (hide the publish drain) ========
    if (t + 1 < TT) {
      const char* pxb = xbuf + ((t + 1) & 3) * 8192 + col * 512
                        + ((quad * 16) ^ ((col & 3) << 4));
      f32x4 tr = {0,0,0,0}, ti = {0,0,0,0};
      #pragma unroll
      for (int ks = 0; ks < 8; ++ks) {
        f16x8 bfr = *reinterpret_cast<const f16x8*>(pxb + ks * 64);
        tr = MFMA16(wxf[ks], bfr, tr);
        ti = MFMA16(wxf[8 + ks], bfr, ti);
      }
      if (p) { gxrA = tr; gxiA = ti; } else { gxrB = tr; gxiB = ti; }
    }
    if (t + 3 < TT) {
      #pragma unroll
      for (int rr = 0; rr < 4; ++rr) {
        int row = w * 4 + rr;
        float4 v = *reinterpret_cast<const float4*>(
            x + ((size_t)(b0 + row) * TT + (t + 3)) * ID + lane * 4);
        store4h((f16*)(xbuf + ((t + 3) & 3) * 8192 + row * 512 + SWZ(row, lane * 8)),
                v.x, v.y, v.z, v.w);
      }
    }

    // ======== drain (publish + ds_writes) then flag ========
    asm volatile("s_waitcnt vmcnt(0) lgkmcnt(0)" ::: "memory");
    if (lane == 0)
      __hip_atomic_store(myflag, t + 1, __ATOMIC_RELAXED, __HIP_MEMORY_SCOPE_SYSTEM);
  }

  // ---- final h export ----
  {
    float4 o; o.x = hm[0]; o.y = hm[1]; o.z = hm[2]; o.w = hm[3];
    *reinterpret_cast<float4*>(hfin + (size_t)(b0 + col) * HH + j0w + row4) = o;
  }
}

// out[b][o] = hfin[b][:] . Wfc[o][:] + bfc[o];  128x256, K=1024.
__global__ __launch_bounds__(64) void fc_kernel(
    const float* __restrict__ hfin, const float* __restrict__ Wfc,
    const float* __restrict__ bfc, float* __restrict__ out)
{
  const int lane = threadIdx.x;
  const int mb = blockIdx.x >> 4, nb = blockIdx.x & 15;
  const int col = lane & 15, row4 = (lane >> 4) * 4;
  const float* pa = hfin + (size_t)(mb * 16 + (lane & 15)) * HH + (lane >> 4) * 8;
  const float* pb = Wfc  + (size_t)(nb * 16 + (lane & 15)) * HH + (lane >> 4) * 8;
  f32x4 acc = {0.f, 0.f, 0.f, 0.f};
  for (int kc = 0; kc < 32; ++kc) {
    f16x8 a, b;
    #pragma unroll
    for (int e = 0; e < 8; ++e) {
      a[e] = (f16)pa[kc * 32 + e];
      b[e] = (f16)pb[kc * 32 + e];
    }
    acc = __builtin_amdgcn_mfma_f32_16x16x32_f16(a, b, acc, 0, 0, 0);
  }
  float bias = bfc[nb * 16 + col];
  #pragma unroll
  for (int r = 0; r < 4; ++r)
    out[(size_t)(mb * 16 + row4 + r) * 256 + nb * 16 + col] = acc[r] + bias;
}

extern "C" void kernel_launch(void* const* d_in, const int* in_sizes, int n_in,
                              void* d_out, int out_size, void* d_ws, size_t ws_size,
                              hipStream_t stream) {
  const float* x   = (const float*)d_in[0];
  const float* Wx  = (const float*)d_in[1];
  const float* bx  = (const float*)d_in[2];
  const float* Wh  = (const float*)d_in[3];
  const float* bh  = (const float*)d_in[4];
  const float* Wfc = (const float*)d_in[5];
  const float* bfc = (const float*)d_in[6];
  float* out = (float*)d_out;

  char* ws = (char*)d_ws;
  f16*   hbuf  = (f16*)ws;                 // 512KB: 2 slots x 256KB
  float* hfin  = (float*)(ws + 524288);    // 512KB
  int*   flags = (int*)(ws + 1048576);     // 32KB ([8][64] x 64B)

  hipMemsetAsync(flags, 0, 32768, stream); // stamps monotone within one run

  (void)hipFuncSetAttribute((const void*)rnn_core,
                            hipFuncAttributeMaxDynamicSharedMemorySize, LDS_SIZE);

  void* args[8];
  args[0] = (void*)&x;    args[1] = (void*)&Wx;   args[2] = (void*)&bx;
  args[3] = (void*)&Wh;   args[4] = (void*)&bh;   args[5] = (void*)&hbuf;
  args[6] = (void*)&hfin; args[7] = (void*)&flags;
  hipError_t err = hipLaunchCooperativeKernel((void*)rnn_core, dim3(128), dim3(256),
                                              args, LDS_SIZE, stream);
  if (err != hipSuccess) {
    rnn_core<<<dim3(128), dim3(256), LDS_SIZE, stream>>>(x, Wx, bx, Wh, bh, hbuf, hfin, flags);
  }

  fc_kernel<<<dim3(128), dim3(64), 0, stream>>>(hfin, Wfc, bfc, out);
}